// Round 1
// 1170.558 us; speedup vs baseline: 1.0381x; 1.0381x over previous
//
#include <hip/hip_runtime.h>
#include <math.h>

#define B_   256
#define L_   196
#define R_   1024
#define E_   1024
#define H_   512
#define G4R  4096   // 4*R
#define DIN  3072   // E + 2R

typedef short v4s __attribute__((ext_vector_type(4)));
typedef short v8s __attribute__((ext_vector_type(8)));
typedef float v4f __attribute__((ext_vector_type(4)));

__device__ __forceinline__ float sigmoidf_(float x) {
    return 1.0f / (1.0f + __expf(-x));
}
__device__ __forceinline__ float tanhf_(float x) {
    float ax = fabsf(x);
    float t  = __expf(-2.0f * ax);
    float r  = (1.0f - t) / (1.0f + t);
    return copysignf(r, x);
}

// split fp32 into two truncated bf16 parts: x ~= hi + lo (error ~2^-14 rel)
__device__ __forceinline__ void split2(float x, short& hi, short& lo) {
    unsigned u = __float_as_uint(x);
    hi = (short)(u >> 16);
    float r = x - __uint_as_float(u & 0xFFFF0000u);
    lo = (short)(__float_as_uint(r) >> 16);
}

// ============================================================================
// Big fused GEMM: gates(B=256, N=4096) = sum over 4 segments (K=1024 each)
//   of Aseg @ Wseg^T, + bias1 + bias2.
// Segments: 3 x-concat pieces against Wih columns {0,1024,2048} + h against Whh.
// 64x64 tile, 256 blocks (1/CU), BK=64, double-buffered LDS with
// register-staged prefetch (loads for tile t+1 in flight while computing t).
// Split-precision bf16 MFMA (3 mfma per frag pair): ~fp32 accuracy.
// ============================================================================
__global__ __launch_bounds__(256) void gemm_big(
    const float* __restrict__ a0, int lda0,
    const float* __restrict__ a1, int lda1,
    const float* __restrict__ a2, int lda2,
    const float* __restrict__ a3, int lda3,
    const float* __restrict__ w0, int ldw0,
    const float* __restrict__ w1, int ldw1,
    const float* __restrict__ w2, int ldw2,
    const float* __restrict__ w3, int ldw3,
    const float* __restrict__ bias1, const float* __restrict__ bias2,
    float* __restrict__ C)
{
    // [buf][Ahi,Alo,Whi,Wlo][row][k]  row stride 72 shorts = 144B:
    // frag-read bank = (4r + 16s + 4q) mod 32 -> only r vs r+8 alias = 2-way (free)
    __shared__ alignas(16) short lds[2][4][64][72];

    const int t     = threadIdx.x;
    const int lane  = t & 63;
    const int wave  = t >> 6;
    const int waveM = wave & 1;
    const int waveN = wave >> 1;
    const int l16   = lane & 15;
    const int quad  = lane >> 4;

    // bijective XCD swizzle: 256 blocks, 8 XCDs -> each XCD gets 8 N-tiles x 4 M-tiles
    // so the 4 M-blocks sharing a W tile are co-resident on one XCD (L2 reuse).
    const int bid = blockIdx.x;
    const int wg  = ((bid & 7) << 5) | (bid >> 3);
    const int mBase = (wg & 3) * 64;
    const int nBase = (wg >> 2) * 64;

    const int rowA = t >> 4;          // + c*16 gives the staged row
    const int kkA  = (t & 15) * 4;    // k offset within the 64-wide tile

    v4f acc[2][2] = {};

    auto loadT = [&](int i, float4* RA, float4* RW) {
        const int s  = i >> 4;
        const int k0 = (i & 15) << 6;
        const float* pa = (s == 0) ? a0 : (s == 1) ? a1 : (s == 2) ? a2 : a3;
        const int    la = (s == 0) ? lda0 : (s == 1) ? lda1 : (s == 2) ? lda2 : lda3;
        const float* pw = (s == 0) ? w0 : (s == 1) ? w1 : (s == 2) ? w2 : w3;
        const int    lw = (s == 0) ? ldw0 : (s == 1) ? ldw1 : (s == 2) ? ldw2 : ldw3;
        pa += (size_t)mBase * la + k0 + kkA;
        pw += (size_t)nBase * lw + k0 + kkA;
#pragma unroll
        for (int c = 0; c < 4; ++c) {
            RA[c] = *(const float4*)(pa + (size_t)(rowA + c * 16) * la);
            RW[c] = *(const float4*)(pw + (size_t)(rowA + c * 16) * lw);
        }
    };

    auto storeT = [&](int buf, const float4* RA, const float4* RW) {
#pragma unroll
        for (int c = 0; c < 4; ++c) {
            const int row = rowA + c * 16;
            short h0, h1, h2, h3, l0, l1, l2, l3;
            split2(RA[c].x, h0, l0); split2(RA[c].y, h1, l1);
            split2(RA[c].z, h2, l2); split2(RA[c].w, h3, l3);
            v4s hv = { h0, h1, h2, h3 };
            v4s lv = { l0, l1, l2, l3 };
            *(v4s*)&lds[buf][0][row][kkA] = hv;
            *(v4s*)&lds[buf][1][row][kkA] = lv;
            split2(RW[c].x, h0, l0); split2(RW[c].y, h1, l1);
            split2(RW[c].z, h2, l2); split2(RW[c].w, h3, l3);
            v4s hw = { h0, h1, h2, h3 };
            v4s lw = { l0, l1, l2, l3 };
            *(v4s*)&lds[buf][2][row][kkA] = hw;
            *(v4s*)&lds[buf][3][row][kkA] = lw;
        }
    };

    auto compT = [&](int buf) {
#pragma unroll
        for (int s = 0; s < 2; ++s) {
            v8s ah[2], al[2], wh[2], wl[2];
#pragma unroll
            for (int fi = 0; fi < 2; ++fi) {
                int r = waveM * 32 + fi * 16 + l16;
                ah[fi] = *(const v8s*)&lds[buf][0][r][s * 32 + quad * 8];
                al[fi] = *(const v8s*)&lds[buf][1][r][s * 32 + quad * 8];
            }
#pragma unroll
            for (int fj = 0; fj < 2; ++fj) {
                int r = waveN * 32 + fj * 16 + l16;
                wh[fj] = *(const v8s*)&lds[buf][2][r][s * 32 + quad * 8];
                wl[fj] = *(const v8s*)&lds[buf][3][r][s * 32 + quad * 8];
            }
#pragma unroll
            for (int fi = 0; fi < 2; ++fi)
#pragma unroll
                for (int fj = 0; fj < 2; ++fj) {
                    acc[fi][fj] = __builtin_amdgcn_mfma_f32_16x16x32_bf16(
                        al[fi], wh[fj], acc[fi][fj], 0, 0, 0);
                    acc[fi][fj] = __builtin_amdgcn_mfma_f32_16x16x32_bf16(
                        ah[fi], wl[fj], acc[fi][fj], 0, 0, 0);
                    acc[fi][fj] = __builtin_amdgcn_mfma_f32_16x16x32_bf16(
                        ah[fi], wh[fj], acc[fi][fj], 0, 0, 0);
                }
        }
    };

    float4 rA0[4], rW0[4], rA1[4], rW1[4];
    loadT(0, rA0, rW0);

#pragma unroll 1
    for (int i = 0; i < 64; i += 2) {
        storeT(0, rA0, rW0);
        loadT(i + 1, rA1, rW1);          // prefetch: in flight across barrier+compute
        __syncthreads();
        compT(0);
        storeT(1, rA1, rW1);
        if (i + 2 < 64) loadT(i + 2, rA0, rW0);
        __syncthreads();
        compT(1);
    }

    // epilogue: C/D layout col=lane&15, row=quad*4+reg
#pragma unroll
    for (int fj = 0; fj < 2; ++fj) {
        int n = nBase + waveN * 32 + fj * 16 + l16;
        float bb = bias1[n] + bias2[n];
#pragma unroll
        for (int fi = 0; fi < 2; ++fi) {
            int m0 = mBase + waveM * 32 + fi * 16 + quad * 4;
#pragma unroll
            for (int r = 0; r < 4; ++r)
                C[(size_t)(m0 + r) * G4R + n] = acc[fi][fj][r] + bb;
        }
    }
}

// ============================================================================
// Small GEMM (att_h = h @ Wh^T + bh): kept from previous version.
// ============================================================================
template<int MT, int NT>
__global__ __launch_bounds__(256) void gemm_mfma(
    const float* __restrict__ A1, const float* __restrict__ W1, int K1, int lda1,
    const float* __restrict__ A2, const float* __restrict__ W2, int K2, int lda2,
    const float* __restrict__ bias1, const float* __restrict__ bias2,
    float* __restrict__ C, int N)
{
    constexpr int FM  = MT / 32;
    constexpr int FN  = NT / 32;
    constexpr int ACH = (MT * 32) / 1024;
    constexpr int WCH = (NT * 32) / 1024;

    __shared__ alignas(16) short Ahi[MT][40];
    __shared__ alignas(16) short Alo[MT][40];
    __shared__ alignas(16) short Whi[NT][40];
    __shared__ alignas(16) short Wlo[NT][40];

    const int t     = threadIdx.x;
    const int lane  = t & 63;
    const int wave  = t >> 6;
    const int waveM = wave & 1;
    const int waveN = wave >> 1;
    const int l16   = lane & 15;
    const int quad  = lane >> 4;
    const int mBase = blockIdx.x * MT;
    const int nBase = blockIdx.y * NT;

    v4f acc[FM][FN] = {};

    for (int seg = 0; seg < 2; ++seg) {
        const int K = seg ? K2 : K1;
        if (K == 0) continue;
        const float* Ag  = seg ? A2 : A1;
        const float* Wg  = seg ? W2 : W1;
        const int    lda = seg ? lda2 : lda1;

        for (int k0 = 0; k0 < K; k0 += 32) {
            __syncthreads();
            #pragma unroll
            for (int c = 0; c < ACH; ++c) {
                int flat = t * 4 + c * 1024;
                int row  = flat >> 5, k = flat & 31;
                float4 v = *(const float4*)(Ag + (size_t)(mBase + row) * lda + k0 + k);
                short h0, h1, h2, h3, l0, l1, l2, l3;
                split2(v.x, h0, l0); split2(v.y, h1, l1);
                split2(v.z, h2, l2); split2(v.w, h3, l3);
                v4s hv = { h0, h1, h2, h3 };
                v4s lv = { l0, l1, l2, l3 };
                *(v4s*)&Ahi[row][k] = hv;
                *(v4s*)&Alo[row][k] = lv;
            }
            #pragma unroll
            for (int c = 0; c < WCH; ++c) {
                int flat = t * 4 + c * 1024;
                int row  = flat >> 5, k = flat & 31;
                float4 v = *(const float4*)(Wg + (size_t)(nBase + row) * K + k0 + k);
                short h0, h1, h2, h3, l0, l1, l2, l3;
                split2(v.x, h0, l0); split2(v.y, h1, l1);
                split2(v.z, h2, l2); split2(v.w, h3, l3);
                v4s hv = { h0, h1, h2, h3 };
                v4s lv = { l0, l1, l2, l3 };
                *(v4s*)&Whi[row][k] = hv;
                *(v4s*)&Wlo[row][k] = lv;
            }
            __syncthreads();

            v8s ah[FM], al[FM], wh[FN], wl[FN];
            #pragma unroll
            for (int fi = 0; fi < FM; ++fi) {
                int r = waveM * (MT / 2) + fi * 16 + l16;
                ah[fi] = *(const v8s*)&Ahi[r][quad * 8];
                al[fi] = *(const v8s*)&Alo[r][quad * 8];
            }
            #pragma unroll
            for (int fj = 0; fj < FN; ++fj) {
                int r = waveN * (NT / 2) + fj * 16 + l16;
                wh[fj] = *(const v8s*)&Whi[r][quad * 8];
                wl[fj] = *(const v8s*)&Wlo[r][quad * 8];
            }

            #pragma unroll
            for (int fi = 0; fi < FM; ++fi)
                #pragma unroll
                for (int fj = 0; fj < FN; ++fj) {
                    acc[fi][fj] = __builtin_amdgcn_mfma_f32_16x16x32_bf16(
                        al[fi], wh[fj], acc[fi][fj], 0, 0, 0);
                    acc[fi][fj] = __builtin_amdgcn_mfma_f32_16x16x32_bf16(
                        ah[fi], wl[fj], acc[fi][fj], 0, 0, 0);
                    acc[fi][fj] = __builtin_amdgcn_mfma_f32_16x16x32_bf16(
                        ah[fi], wh[fj], acc[fi][fj], 0, 0, 0);
                }
        }
    }

    #pragma unroll
    for (int fj = 0; fj < FN; ++fj) {
        int n = nBase + waveN * (NT / 2) + fj * 16 + l16;
        float bb = bias1[n] + (bias2 ? bias2[n] : 0.0f);
        #pragma unroll
        for (int fi = 0; fi < FM; ++fi) {
            int m0 = mBase + waveM * (MT / 2) + fi * 16 + quad * 4;
            #pragma unroll
            for (int r = 0; r < 4; ++r)
                C[(size_t)(m0 + r) * N + n] = acc[fi][fj][r] + bb;
        }
    }
}

// gates (B,4R) + c_in (B,R) -> h_out, c_out (B,R); optional mirror of h.
__global__ __launch_bounds__(256) void lstm_cell(
    const float* __restrict__ gates, const float* __restrict__ c_in,
    float* __restrict__ h_out, float* __restrict__ c_out,
    float* __restrict__ h_out2)
{
    int e = blockIdx.x * 256 + threadIdx.x;
    int b = e >> 10;
    int j = e & 1023;
    const float* g = gates + (size_t)b * G4R;
    float i_ = sigmoidf_(g[j]);
    float f_ = sigmoidf_(g[j + 1024]);
    float gg = tanhf_(g[j + 2048]);
    float o_ = sigmoidf_(g[j + 3072]);
    float c  = f_ * c_in[e] + i_ * gg;
    float h  = o_ * tanhf_(c);
    c_out[e] = c;
    h_out[e] = h;
    if (h_out2) h_out2[e] = h;
}

// scores[b,l] = sum_h tanh(p[b,l,h] + att_h[b,h]) * Wa[h] + ba
__global__ __launch_bounds__(64) void attn_scores(
    const float* __restrict__ p_att,
    const float* __restrict__ att_h,
    const float* __restrict__ Wa,
    const float* __restrict__ ba,
    float* __restrict__ scores)
{
    int l = blockIdx.x;
    int b = blockIdx.y;
    int lane = threadIdx.x;
    const float* p  = p_att + ((size_t)b * L_ + l) * H_;
    const float* ah = att_h + (size_t)b * H_;
    float sum = 0.0f;
#pragma unroll
    for (int i = 0; i < H_ / 64; i++) {
        int h = lane + i * 64;
        sum += tanhf_(p[h] + ah[h]) * Wa[h];
    }
    for (int off = 32; off; off >>= 1) sum += __shfl_down(sum, off);
    if (lane == 0) scores[(size_t)b * L_ + l] = sum + ba[0];
}

// w = softmax(scores, axis=1); w *= mask; w /= (sum(w)+1e-10)
__global__ __launch_bounds__(256) void attn_softmax(
    const float* __restrict__ scores, const float* __restrict__ mask,
    float* __restrict__ w)
{
    int b = blockIdx.x;
    int t = threadIdx.x;
    __shared__ float red[256];
    float v = (t < L_) ? scores[(size_t)b * L_ + t] : -1e30f;
    red[t] = v; __syncthreads();
    for (int s = 128; s; s >>= 1) {
        if (t < s) red[t] = fmaxf(red[t], red[t + s]);
        __syncthreads();
    }
    float mx = red[0]; __syncthreads();
    float e = (t < L_) ? __expf(v - mx) : 0.0f;
    red[t] = e; __syncthreads();
    for (int s = 128; s; s >>= 1) {
        if (t < s) red[t] += red[t + s];
        __syncthreads();
    }
    float denom = red[0]; __syncthreads();
    float wm = (t < L_) ? (e / denom) * mask[(size_t)b * L_ + t] : 0.0f;
    red[t] = wm; __syncthreads();
    for (int s = 128; s; s >>= 1) {
        if (t < s) red[t] += red[t + s];
        __syncthreads();
    }
    float denom2 = red[0] + 1e-10f;
    if (t < L_) w[(size_t)b * L_ + t] = wm / denom2;
}

// out[b,r] = sum_l w[b,l] * feats[b,l,r]
__global__ __launch_bounds__(256) void attn_wsum(
    const float* __restrict__ w,
    const float* __restrict__ feats,
    float* __restrict__ out)
{
    int b = blockIdx.y;
    int r = blockIdx.x * 256 + threadIdx.x;
    __shared__ float ws[L_];
    for (int i = threadIdx.x; i < L_; i += 256)
        ws[i] = w[(size_t)b * L_ + i];
    __syncthreads();
    const float* f = feats + (size_t)b * L_ * R_ + r;
    float a0 = 0, a1 = 0, a2 = 0, a3 = 0;
    for (int l = 0; l < L_; l += 4) {
        a0 += ws[l + 0] * f[(size_t)(l + 0) * R_];
        a1 += ws[l + 1] * f[(size_t)(l + 1) * R_];
        a2 += ws[l + 2] * f[(size_t)(l + 2) * R_];
        a3 += ws[l + 3] * f[(size_t)(l + 3) * R_];
    }
    out[(size_t)b * R_ + r] = a0 + a1 + a2 + a3;
}

extern "C" void kernel_launch(void* const* d_in, const int* in_sizes, int n_in,
                              void* d_out, int out_size, void* d_ws, size_t ws_size,
                              hipStream_t stream)
{
    const float* xt         = (const float*)d_in[0];
    const float* fc_feats   = (const float*)d_in[1];
    const float* att_feats  = (const float*)d_in[2];
    const float* p_att      = (const float*)d_in[3];
    const float* mask       = (const float*)d_in[4];
    const float* att_feats1 = (const float*)d_in[5];
    const float* p_att1     = (const float*)d_in[6];
    const float* mask1      = (const float*)d_in[7];
    const float* state_h    = (const float*)d_in[8];
    const float* state_c    = (const float*)d_in[9];
    const float* Wih0 = (const float*)d_in[10];
    const float* Whh0 = (const float*)d_in[11];
    const float* bih0 = (const float*)d_in[12];
    const float* bhh0 = (const float*)d_in[13];
    const float* Wih1 = (const float*)d_in[14];
    const float* Whh1 = (const float*)d_in[15];
    const float* bih1 = (const float*)d_in[16];
    const float* bhh1 = (const float*)d_in[17];
    const float* WihL = (const float*)d_in[18];
    const float* WhhL = (const float*)d_in[19];
    const float* bihL = (const float*)d_in[20];
    const float* bhhL = (const float*)d_in[21];
    const float* a0_Wh = (const float*)d_in[22];
    const float* a0_bh = (const float*)d_in[23];
    const float* a0_Wa = (const float*)d_in[24];
    const float* a0_ba = (const float*)d_in[25];
    const float* a_Wh  = (const float*)d_in[26];
    const float* a_bh  = (const float*)d_in[27];
    const float* a_Wa  = (const float*)d_in[28];
    const float* a_ba  = (const float*)d_in[29];
    const float* a1_Wh = (const float*)d_in[30];
    const float* a1_bh = (const float*)d_in[31];
    const float* a1_Wa = (const float*)d_in[32];
    const float* a1_ba = (const float*)d_in[33];

    const size_t BR = (size_t)B_ * R_;
    float* out   = (float*)d_out;
    float* h0    = out + 1 * BR;
    float* h1    = out + 2 * BR;
    float* h2    = out + 3 * BR;
    float* c0    = out + 4 * BR;
    float* c1    = out + 5 * BR;
    float* c2    = out + 6 * BR;

    float* xbuf  = (float*)d_ws;                          // (unused, kept for layout)
    float* gates = xbuf + (size_t)B_ * DIN;               // B*4096
    float* atth  = gates + (size_t)B_ * G4R;              // B*H
    float* sc    = atth + (size_t)B_ * H_;                // B*L
    float* att0  = sc + (size_t)B_ * L_;                  // B*R
    float* attA  = att0 + BR;                             // B*R
    float* attB  = attA + BR;                             // B*R

    const float* prev_h = state_h + 2 * BR;

    dim3 gA(B_ / 32, H_ / 32);    // att_h MFMA grid: 8 x 16
    dim3 gS(L_, B_);              // scores grid
    dim3 gW(R_ / 256, B_);        // wsum grid

    // ---- stage 0: LSTM att0 (x0 = [prev_h | fc | xt], h = state_h[0]) ----
    gemm_big<<<256, 256, 0, stream>>>(
        prev_h, R_, fc_feats, 3 * R_, xt, E_, state_h, R_,
        Wih0, DIN, Wih0 + 1024, DIN, Wih0 + 2048, DIN, Whh0, R_,
        bih0, bhh0, gates);
    lstm_cell<<<(B_ * R_) / 256, 256, 0, stream>>>(gates, state_c, h0, c0, nullptr);

    // ---- attention 0 (feats1, params a0) ----
    gemm_mfma<32, 32><<<gA, 256, 0, stream>>>(h0, a0_Wh, R_, R_,
                                              nullptr, nullptr, 0, 0,
                                              a0_bh, nullptr, atth, H_);
    attn_scores<<<gS, 64, 0, stream>>>(p_att1, atth, a0_Wa, a0_ba, sc);
    attn_softmax<<<B_, 256, 0, stream>>>(sc, mask1, sc);
    attn_wsum<<<gW, 256, 0, stream>>>(sc, att_feats1, att0);

    // ---- stage 1: LSTM att (x1 = [prev_h | att0 | xt], h = state_h[1]) ----
    gemm_big<<<256, 256, 0, stream>>>(
        prev_h, R_, att0, R_, xt, E_, state_h + BR, R_,
        Wih1, DIN, Wih1 + 1024, DIN, Wih1 + 2048, DIN, Whh1, R_,
        bih1, bhh1, gates);
    lstm_cell<<<(B_ * R_) / 256, 256, 0, stream>>>(gates, state_c + BR, h1, c1, nullptr);

    // ---- attention a (feats, params a) -> attA ----
    gemm_mfma<32, 32><<<gA, 256, 0, stream>>>(h1, a_Wh, R_, R_,
                                              nullptr, nullptr, 0, 0,
                                              a_bh, nullptr, atth, H_);
    attn_scores<<<gS, 64, 0, stream>>>(p_att, atth, a_Wa, a_ba, sc);
    attn_softmax<<<B_, 256, 0, stream>>>(sc, mask, sc);
    attn_wsum<<<gW, 256, 0, stream>>>(sc, att_feats, attA);

    // ---- attention a1 (feats1, params a1) -> attB ----
    gemm_mfma<32, 32><<<gA, 256, 0, stream>>>(h1, a1_Wh, R_, R_,
                                              nullptr, nullptr, 0, 0,
                                              a1_bh, nullptr, atth, H_);
    attn_scores<<<gS, 64, 0, stream>>>(p_att1, atth, a1_Wa, a1_ba, sc);
    attn_softmax<<<B_, 256, 0, stream>>>(sc, mask1, sc);
    attn_wsum<<<gW, 256, 0, stream>>>(sc, att_feats1, attB);

    // ---- stage 2: LSTM lang (xL = [attA | attB | h1], h = state_h[2]) ----
    gemm_big<<<256, 256, 0, stream>>>(
        attA, R_, attB, R_, h1, R_, state_h + 2 * BR, R_,
        WihL, DIN, WihL + 1024, DIN, WihL + 2048, DIN, WhhL, R_,
        bihL, bhhL, gates);
    lstm_cell<<<(B_ * R_) / 256, 256, 0, stream>>>(gates, state_c + 2 * BR, h2, c2, out);
}